// Round 1
// baseline (879.903 us; speedup 1.0000x reference)
//
#include <hip/hip_runtime.h>

#define RES 256
#define NFEAT 65536
#define FDIM 16

// One thread per point: gather/interp from hash grid, then 5 small matmuls on
// the fp32 vector ALU. Weight reads are wave-uniform -> scalar loads (SGPR
// operand in v_fmac), no LDS staging needed.
__global__ __launch_bounds__(256) void lh_fused(
    const float* __restrict__ pts, const float* __restrict__ rds,
    const float* __restrict__ G,   const float* __restrict__ F,
    const float* __restrict__ Ws1, const float* __restrict__ Ws2,
    const float* __restrict__ Wc1, const float* __restrict__ Wc2,
    const float* __restrict__ Wc3,
    float* __restrict__ sig_out, float* __restrict__ col_out, int N)
{
    const int n = blockIdx.x * blockDim.x + threadIdx.x;
    if (n >= N) return;

    const float px = pts[3*n+0], py = pts[3*n+1], pz = pts[3*n+2];

    // post_floor for the two candidate coords per dim, clipped to [0, RES-1].
    float fx0 = fminf(fmaxf(floorf(px - 0.5f), 0.f), 255.f);
    float fy0 = fminf(fmaxf(floorf(py - 0.5f), 0.f), 255.f);
    float fz0 = fminf(fmaxf(floorf(pz - 0.5f), 0.f), 255.f);
    float fx1 = fminf(fmaxf(floorf(px + 0.5f), 0.f), 255.f);
    float fy1 = fminf(fmaxf(floorf(py + 0.5f), 0.f), 255.f);
    float fz1 = fminf(fmaxf(floorf(pz + 0.5f), 0.f), 255.f);

    const int ixs[2] = { (int)fx0, (int)fx1 };
    const int iys[2] = { (int)fy0, (int)fy1 };
    const int izs[2] = { (int)fz0, (int)fz1 };

    // offsets = pts - post_floor[neighbor 0]  (the -0.5 corner, post-clip)
    const float ox = px - fx0, oy = py - fy0, oz = pz - fz0;
    const float wxs[2] = { 1.f - ox, ox };
    const float wys[2] = { 1.f - oy, oy };
    const float wzs[2] = { 1.f - oz, oz };

    float fv[FDIM];
    #pragma unroll
    for (int d = 0; d < FDIM; ++d) fv[d] = 0.f;

    // 8 neighbors: gather G, map to feature index, lerp two F rows, accumulate.
    #pragma unroll
    for (int k = 0; k < 8; ++k) {
        const int bx = (k >> 2) & 1, by = (k >> 1) & 1, bz = k & 1;
        float g = G[(ixs[bx] * RES + iys[by]) * RES + izs[bz]];
        g = fminf(fmaxf(g, -1.f), 1.f);
        const float Fi  = (g + 1.f) * 32768.f;          // [0, 65536]
        const float Fif = fminf(floorf(Fi), 65535.f);   // floor >= 0 already
        const float Fic = fminf(ceilf(Fi),  65535.f);
        const float wf = Fic - Fi;   // weights from CLIPPED indices (ref exact:
        const float wc = Fi - Fif;   // integer Fi -> both 0 -> zero contribution)
        const float wk = wxs[bx] * wys[by] * wzs[bz];

        const float4* rf = (const float4*)(F + (int)Fif * FDIM);
        const float4* rc = (const float4*)(F + (int)Fic * FDIM);
        #pragma unroll
        for (int q = 0; q < 4; ++q) {
            const float4 a = rf[q];
            const float4 b = rc[q];
            fv[4*q+0] = fmaf(wk, fmaf(wf, a.x, wc * b.x), fv[4*q+0]);
            fv[4*q+1] = fmaf(wk, fmaf(wf, a.y, wc * b.y), fv[4*q+1]);
            fv[4*q+2] = fmaf(wk, fmaf(wf, a.z, wc * b.z), fv[4*q+2]);
            fv[4*q+3] = fmaf(wk, fmaf(wf, a.w, wc * b.w), fv[4*q+3]);
        }
    }

    // ---- sigma MLP: h = relu(fv @ Ws1) ; fv2 = h @ Ws2 ----
    float h[64];
    #pragma unroll
    for (int j = 0; j < 64; ++j) h[j] = 0.f;
    for (int i = 0; i < 16; ++i) {
        const float x = fv[i];
        const float* __restrict__ row = Ws1 + i * 64;
        #pragma unroll
        for (int j = 0; j < 64; ++j) h[j] = fmaf(x, row[j], h[j]);
    }
    #pragma unroll
    for (int j = 0; j < 64; ++j) h[j] = fmaxf(h[j], 0.f);

    float fv2[16];
    #pragma unroll
    for (int d = 0; d < 16; ++d) fv2[d] = 0.f;
    for (int i = 0; i < 64; ++i) {
        const float x = h[i];
        const float* __restrict__ row = Ws2 + i * 16;
        #pragma unroll
        for (int d = 0; d < 16; ++d) fv2[d] = fmaf(x, row[d], fv2[d]);
    }

    sig_out[n] = fv2[0];

    // ---- SH degree-4 encoding of ray dir ----
    const float dx = rds[3*n+0], dy = rds[3*n+1], dz = rds[3*n+2];
    const float x2 = dx*dx, y2 = dy*dy, z2 = dz*dz;
    float cin[31];
    cin[0]  = 0.28209479177387814f;
    cin[1]  = -0.48860251190291987f * dy;
    cin[2]  =  0.48860251190291987f * dz;
    cin[3]  = -0.48860251190291987f * dx;
    cin[4]  =  1.0925484305920792f * dx * dy;
    cin[5]  = -1.0925484305920792f * dy * dz;
    cin[6]  =  0.94617469575756f * z2 - 0.31539156525252005f;
    cin[7]  = -1.0925484305920792f * dx * dz;
    cin[8]  =  0.5462742152960396f * (x2 - y2);
    cin[9]  =  0.5900435899266435f * dy * (-3.0f * x2 + y2);
    cin[10] =  2.890611442640554f * dx * dy * dz;
    cin[11] =  0.4570457994644657f * dy * (1.0f - 5.0f * z2);
    cin[12] =  0.3731763325901154f * dz * (5.0f * z2 - 3.0f);
    cin[13] =  0.4570457994644657f * dx * (1.0f - 5.0f * z2);
    cin[14] =  1.445305721320277f * dz * (x2 - y2);
    cin[15] =  0.5900435899266435f * dx * (-x2 + 3.0f * y2);
    #pragma unroll
    for (int d = 1; d < 16; ++d) cin[16 + d - 1] = fv2[d];

    // ---- color MLP: c1 = relu(cin @ Wc1); c2 = relu(c1 @ Wc2); col = c2 @ Wc3 ----
    float c1[64];
    #pragma unroll
    for (int j = 0; j < 64; ++j) c1[j] = 0.f;
    for (int i = 0; i < 31; ++i) {
        const float x = cin[i];
        const float* __restrict__ row = Wc1 + i * 64;
        #pragma unroll
        for (int j = 0; j < 64; ++j) c1[j] = fmaf(x, row[j], c1[j]);
    }
    #pragma unroll
    for (int j = 0; j < 64; ++j) c1[j] = fmaxf(c1[j], 0.f);

    float c2[64];
    #pragma unroll
    for (int j = 0; j < 64; ++j) c2[j] = 0.f;
    for (int i = 0; i < 64; ++i) {
        const float x = c1[i];
        const float* __restrict__ row = Wc2 + i * 64;
        #pragma unroll
        for (int j = 0; j < 64; ++j) c2[j] = fmaf(x, row[j], c2[j]);
    }
    #pragma unroll
    for (int j = 0; j < 64; ++j) c2[j] = fmaxf(c2[j], 0.f);

    float col0 = 0.f, col1 = 0.f, col2 = 0.f;
    for (int i = 0; i < 64; ++i) {
        const float x = c2[i];
        const float* __restrict__ row = Wc3 + i * 3;
        col0 = fmaf(x, row[0], col0);
        col1 = fmaf(x, row[1], col1);
        col2 = fmaf(x, row[2], col2);
    }
    col_out[3*n+0] = col0;
    col_out[3*n+1] = col1;
    col_out[3*n+2] = col2;
}

extern "C" void kernel_launch(void* const* d_in, const int* in_sizes, int n_in,
                              void* d_out, int out_size, void* d_ws, size_t ws_size,
                              hipStream_t stream) {
    const float* pts = (const float*)d_in[0];
    const float* rds = (const float*)d_in[1];
    const float* G   = (const float*)d_in[2];
    const float* F   = (const float*)d_in[3];
    const float* Ws1 = (const float*)d_in[4];
    const float* Ws2 = (const float*)d_in[5];
    const float* Wc1 = (const float*)d_in[6];
    const float* Wc2 = (const float*)d_in[7];
    const float* Wc3 = (const float*)d_in[8];

    const int N = in_sizes[0] / 3;  // 1,000,000 points
    float* sig = (float*)d_out;           // [N]
    float* col = (float*)d_out + N;       // [N,3] row-major

    const int block = 256;
    const int grid  = (N + block - 1) / block;
    lh_fused<<<grid, block, 0, stream>>>(pts, rds, G, F, Ws1, Ws2, Wc1, Wc2, Wc3,
                                         sig, col, N);
}

// Round 2
// 641.693 us; speedup vs baseline: 1.3712x; 1.3712x over previous
//
#include <hip/hip_runtime.h>

#define RES 256
#define NFEAT 65536
#define FDIM 16

// One thread per point, fully fused. ALL activation arrays statically indexed
// (full unroll) so they live in VGPRs -- rolled outer loops put them in
// scratch last round (480 MB spill writes). Peak live set is capped by
// splitting the c2 phase into two 32-wide halves with relu+Wc3 fused, so
// c2[64] is never materialized alongside c1[64].
// __launch_bounds__(256,3): VGPR cap 170, 3 waves/SIMD.
__global__ __launch_bounds__(256, 3) void lh_fused(
    const float* __restrict__ pts, const float* __restrict__ rds,
    const float* __restrict__ G,   const float* __restrict__ F,
    const float* __restrict__ Ws1, const float* __restrict__ Ws2,
    const float* __restrict__ Wc1, const float* __restrict__ Wc2,
    const float* __restrict__ Wc3,
    float* __restrict__ sig_out, float* __restrict__ col_out, int N)
{
    const int n = blockIdx.x * blockDim.x + threadIdx.x;
    if (n >= N) return;

    const float px = pts[3*n+0], py = pts[3*n+1], pz = pts[3*n+2];

    // post_floor for the two candidate coords per dim, clipped to [0, RES-1].
    const float fx0 = fminf(fmaxf(floorf(px - 0.5f), 0.f), 255.f);
    const float fy0 = fminf(fmaxf(floorf(py - 0.5f), 0.f), 255.f);
    const float fz0 = fminf(fmaxf(floorf(pz - 0.5f), 0.f), 255.f);
    const float fx1 = fminf(fmaxf(floorf(px + 0.5f), 0.f), 255.f);
    const float fy1 = fminf(fmaxf(floorf(py + 0.5f), 0.f), 255.f);
    const float fz1 = fminf(fmaxf(floorf(pz + 0.5f), 0.f), 255.f);

    const int ixs[2] = { (int)fx0, (int)fx1 };
    const int iys[2] = { (int)fy0, (int)fy1 };
    const int izs[2] = { (int)fz0, (int)fz1 };

    // offsets = pts - post_floor[neighbor 0]  (the -0.5 corner, post-clip)
    const float ox = px - fx0, oy = py - fy0, oz = pz - fz0;
    const float wxs[2] = { 1.f - ox, ox };
    const float wys[2] = { 1.f - oy, oy };
    const float wzs[2] = { 1.f - oz, oz };

    float fv[FDIM];
    #pragma unroll
    for (int d = 0; d < FDIM; ++d) fv[d] = 0.f;

    // 8 neighbors: gather G, map to feature index, lerp two F rows, accumulate.
    #pragma unroll
    for (int k = 0; k < 8; ++k) {
        const int bx = (k >> 2) & 1, by = (k >> 1) & 1, bz = k & 1;
        float g = G[(ixs[bx] * RES + iys[by]) * RES + izs[bz]];
        g = fminf(fmaxf(g, -1.f), 1.f);
        const float Fi  = (g + 1.f) * 32768.f;          // [0, 65536]
        const float Fif = fminf(floorf(Fi), 65535.f);
        const float Fic = fminf(ceilf(Fi),  65535.f);
        const float wf = Fic - Fi;   // weights from CLIPPED indices (matches ref)
        const float wc = Fi - Fif;
        const float wk = wxs[bx] * wys[by] * wzs[bz];

        const float4* rf = (const float4*)(F + (int)Fif * FDIM);
        const float4* rc = (const float4*)(F + (int)Fic * FDIM);
        #pragma unroll
        for (int q = 0; q < 4; ++q) {
            const float4 a = rf[q];
            const float4 b = rc[q];
            fv[4*q+0] = fmaf(wk, fmaf(wf, a.x, wc * b.x), fv[4*q+0]);
            fv[4*q+1] = fmaf(wk, fmaf(wf, a.y, wc * b.y), fv[4*q+1]);
            fv[4*q+2] = fmaf(wk, fmaf(wf, a.z, wc * b.z), fv[4*q+2]);
            fv[4*q+3] = fmaf(wk, fmaf(wf, a.w, wc * b.w), fv[4*q+3]);
        }
    }

    // ---- sigma MLP: h = relu(fv @ Ws1) ----  (live: fv16 + h64)
    float h[64];
    #pragma unroll
    for (int j = 0; j < 64; ++j) h[j] = 0.f;
    #pragma unroll
    for (int i = 0; i < 16; ++i) {
        const float x = fv[i];
        const float* __restrict__ row = Ws1 + i * 64;
        #pragma unroll
        for (int j = 0; j < 64; ++j) h[j] = fmaf(x, row[j], h[j]);
    }
    #pragma unroll
    for (int j = 0; j < 64; ++j) h[j] = fmaxf(h[j], 0.f);

    // ---- fv2 = h @ Ws2 ----  (live: h64 + fv2_16)
    float fv2[16];
    #pragma unroll
    for (int d = 0; d < 16; ++d) fv2[d] = 0.f;
    #pragma unroll
    for (int i = 0; i < 64; ++i) {
        const float x = h[i];
        const float* __restrict__ row = Ws2 + i * 16;
        #pragma unroll
        for (int d = 0; d < 16; ++d) fv2[d] = fmaf(x, row[d], fv2[d]);
    }

    sig_out[n] = fv2[0];

    // ---- SH degree-4 encoding + concat ----
    const float dx = rds[3*n+0], dy = rds[3*n+1], dz = rds[3*n+2];
    const float x2 = dx*dx, y2 = dy*dy, z2 = dz*dz;
    float cin[31];
    cin[0]  = 0.28209479177387814f;
    cin[1]  = -0.48860251190291987f * dy;
    cin[2]  =  0.48860251190291987f * dz;
    cin[3]  = -0.48860251190291987f * dx;
    cin[4]  =  1.0925484305920792f * dx * dy;
    cin[5]  = -1.0925484305920792f * dy * dz;
    cin[6]  =  0.94617469575756f * z2 - 0.31539156525252005f;
    cin[7]  = -1.0925484305920792f * dx * dz;
    cin[8]  =  0.5462742152960396f * (x2 - y2);
    cin[9]  =  0.5900435899266435f * dy * (-3.0f * x2 + y2);
    cin[10] =  2.890611442640554f * dx * dy * dz;
    cin[11] =  0.4570457994644657f * dy * (1.0f - 5.0f * z2);
    cin[12] =  0.3731763325901154f * dz * (5.0f * z2 - 3.0f);
    cin[13] =  0.4570457994644657f * dx * (1.0f - 5.0f * z2);
    cin[14] =  1.445305721320277f * dz * (x2 - y2);
    cin[15] =  0.5900435899266435f * dx * (-x2 + 3.0f * y2);
    #pragma unroll
    for (int d = 1; d < 16; ++d) cin[16 + d - 1] = fv2[d];

    // ---- c1 = relu(cin @ Wc1) ----  (live: cin31 + c1_64)
    float c1[64];
    #pragma unroll
    for (int j = 0; j < 64; ++j) c1[j] = 0.f;
    #pragma unroll
    for (int i = 0; i < 31; ++i) {
        const float x = cin[i];
        const float* __restrict__ row = Wc1 + i * 64;
        #pragma unroll
        for (int j = 0; j < 64; ++j) c1[j] = fmaf(x, row[j], c1[j]);
    }
    #pragma unroll
    for (int j = 0; j < 64; ++j) c1[j] = fmaxf(c1[j], 0.f);

    // ---- c2 = relu(c1 @ Wc2); col = c2 @ Wc3 ----
    // Two 32-wide halves with relu+Wc3 fused: c2 never fully live.
    // (live: c1_64 + c2h_32 + col3)
    float col0 = 0.f, col1 = 0.f, col2 = 0.f;
    #pragma unroll
    for (int half = 0; half < 2; ++half) {
        float c2h[32];
        #pragma unroll
        for (int j = 0; j < 32; ++j) c2h[j] = 0.f;
        #pragma unroll
        for (int i = 0; i < 64; ++i) {
            const float x = c1[i];
            const float* __restrict__ row = Wc2 + i * 64 + half * 32;
            #pragma unroll
            for (int j = 0; j < 32; ++j) c2h[j] = fmaf(x, row[j], c2h[j]);
        }
        #pragma unroll
        for (int j = 0; j < 32; ++j) {
            const float x = fmaxf(c2h[j], 0.f);
            const float* __restrict__ row = Wc3 + (half * 32 + j) * 3;
            col0 = fmaf(x, row[0], col0);
            col1 = fmaf(x, row[1], col1);
            col2 = fmaf(x, row[2], col2);
        }
    }

    col_out[3*n+0] = col0;
    col_out[3*n+1] = col1;
    col_out[3*n+2] = col2;
}

extern "C" void kernel_launch(void* const* d_in, const int* in_sizes, int n_in,
                              void* d_out, int out_size, void* d_ws, size_t ws_size,
                              hipStream_t stream) {
    const float* pts = (const float*)d_in[0];
    const float* rds = (const float*)d_in[1];
    const float* G   = (const float*)d_in[2];
    const float* F   = (const float*)d_in[3];
    const float* Ws1 = (const float*)d_in[4];
    const float* Ws2 = (const float*)d_in[5];
    const float* Wc1 = (const float*)d_in[6];
    const float* Wc2 = (const float*)d_in[7];
    const float* Wc3 = (const float*)d_in[8];

    const int N = in_sizes[0] / 3;  // 1,000,000 points
    float* sig = (float*)d_out;           // [N]
    float* col = (float*)d_out + N;       // [N,3]

    const int block = 256;
    const int grid  = (N + block - 1) / block;
    lh_fused<<<grid, block, 0, stream>>>(pts, rds, G, F, Ws1, Ws2, Wc1, Wc2, Wc3,
                                         sig, col, N);
}